// Round 5
// baseline (724.997 us; speedup 1.0000x reference)
//
#include <hip/hip_runtime.h>
#include <hip/hip_bf16.h>
#include <stdint.h>

typedef unsigned short u16;
typedef uint32_t u32;
typedef __attribute__((ext_vector_type(8))) short s8v;   // 8 bf16 (4 VGPRs)
typedef __attribute__((ext_vector_type(4))) float f4v;   // 4 fp32
typedef __attribute__((ext_vector_type(4))) unsigned int u4v;

#define SQ   2048
#define HDIM 2048
#define HD_  128
#define NH_  16
#define NKV_ 8

__device__ __forceinline__ u16 f2b(float f) {
  uint32_t u = __builtin_bit_cast(uint32_t, f);
  u += 0x7fffu + ((u >> 16) & 1u);
  return (u16)(u >> 16);
}
__device__ __forceinline__ float b2f(u16 v) {
  uint32_t u = ((uint32_t)v) << 16;
  return __builtin_bit_cast(float, u);
}
__device__ __forceinline__ u32 pk2(float lo, float hi) {
  return (u32)f2b(lo) | ((u32)f2b(hi) << 16);
}

// ---------------- cast f32 -> bf16, 4 elems/thread ----------------
__global__ __launch_bounds__(256) void k_cast(const float* __restrict__ in,
                                              u16* __restrict__ out, int n4) {
  int i = blockIdx.x * 256 + threadIdx.x;
  if (i >= n4) return;
  f4v v = *(const f4v*)(in + (size_t)i * 4);
  union { u16 s[4]; uint64_t u; } o;
  o.s[0] = f2b(v[0]); o.s[1] = f2b(v[1]); o.s[2] = f2b(v[2]); o.s[3] = f2b(v[3]);
  *(uint64_t*)(out + (size_t)i * 4) = o.u;
}

// ---------------- fused transpose+cast for all 4 weights ----------------
// rows = 2048 always; z selects {wq:2048, wk:1024, wv:1024, wo:2048} cols.
__global__ __launch_bounds__(256) void k_transpose4(const float* __restrict__ wq,
                                                    const float* __restrict__ wk,
                                                    const float* __restrict__ wv,
                                                    const float* __restrict__ wo,
                                                    u16* __restrict__ wqt,
                                                    u16* __restrict__ wkt,
                                                    u16* __restrict__ wvt,
                                                    u16* __restrict__ wot) {
  const int z = blockIdx.z;
  const float* in = (z == 0) ? wq : (z == 1) ? wk : (z == 2) ? wv : wo;
  u16* out = (z == 0) ? wqt : (z == 1) ? wkt : (z == 2) ? wvt : wot;
  const int cols = (z == 1 || z == 2) ? 1024 : 2048;
  int c0 = blockIdx.x * 32, r0 = blockIdx.y * 32;
  if (c0 >= cols) return;
  __shared__ float tile[32][33];
  int tx = threadIdx.x & 31, ty = threadIdx.x >> 5;
#pragma unroll
  for (int i = 0; i < 32; i += 8)
    tile[ty + i][tx] = in[(size_t)(r0 + ty + i) * cols + c0 + tx];
  __syncthreads();
#pragma unroll
  for (int i = 0; i < 32; i += 8)
    out[(size_t)(c0 + ty + i) * 2048 + r0 + tx] = f2b(tile[tx][ty + i]);
}

// ---------------- bf16 GEMM: C[M,N] = A[M,K] * Bt[N,K]^T ----------------
// 128x128 tile, BK=64, 4 waves. global_load_lds staging, rule-21 swizzle.
template <int F32OUT>
__global__ __launch_bounds__(256) void k_gemm(const u16* __restrict__ A,
                                              const u16* __restrict__ Bt,
                                              void* __restrict__ C,
                                              int M, int N, int K) {
  __shared__ __align__(16) u16 As[128 * 64];
  __shared__ __align__(16) u16 Bs[128 * 64];
  const int tid = threadIdx.x;
  const int lane = tid & 63, wvi = tid >> 6;
  const int wm = wvi >> 1, wn = wvi & 1;
  const int l15 = lane & 15, l4 = lane >> 4;
  const int m0 = blockIdx.y * 128, n0 = blockIdx.x * 128;
  auto* As3 = (__attribute__((address_space(3))) char*)As;
  auto* Bs3 = (__attribute__((address_space(3))) char*)Bs;
  int srow[4], soff[4];
#pragma unroll
  for (int i = 0; i < 4; i++) {
    int slot = wvi * 4096 + i * 1024 + lane * 16;
    int r = slot >> 7;
    int gc = ((slot >> 4) & 7) ^ (r & 7);
    srow[i] = r; soff[i] = gc * 16;
  }
  f4v acc[4][4] = {};
  for (int k0 = 0; k0 < K; k0 += 64) {
#pragma unroll
    for (int i = 0; i < 4; i++) {
      const char* gA = (const char*)(A + (size_t)(m0 + srow[i]) * K + k0) + soff[i];
      const char* gB = (const char*)(Bt + (size_t)(n0 + srow[i]) * K + k0) + soff[i];
      __builtin_amdgcn_global_load_lds((__attribute__((address_space(1))) void*)gA,
                                       (__attribute__((address_space(3))) void*)(As3 + wvi * 4096 + i * 1024),
                                       16, 0, 0);
      __builtin_amdgcn_global_load_lds((__attribute__((address_space(1))) void*)gB,
                                       (__attribute__((address_space(3))) void*)(Bs3 + wvi * 4096 + i * 1024),
                                       16, 0, 0);
    }
    __syncthreads();
#pragma unroll
    for (int kk = 0; kk < 2; kk++) {
      s8v af[4], bf[4];
#pragma unroll
      for (int i = 0; i < 4; i++) {
        int ra = wm * 64 + i * 16 + l15;
        af[i] = *(const s8v*)((const char*)As + ra * 128 +
                              ((kk * 64 + l4 * 16) ^ ((ra & 7) << 4)));
        int rb = wn * 64 + i * 16 + l15;
        bf[i] = *(const s8v*)((const char*)Bs + rb * 128 +
                              ((kk * 64 + l4 * 16) ^ ((rb & 7) << 4)));
      }
#pragma unroll
      for (int i = 0; i < 4; i++)
#pragma unroll
        for (int j = 0; j < 4; j++)
          acc[i][j] = __builtin_amdgcn_mfma_f32_16x16x32_bf16(af[i], bf[j], acc[i][j], 0, 0, 0);
    }
    __syncthreads();
  }
#pragma unroll
  for (int i = 0; i < 4; i++) {
#pragma unroll
    for (int j = 0; j < 4; j++) {
      int mb = m0 + wm * 64 + i * 16 + l4 * 4;
      int nn = n0 + wn * 64 + j * 16 + l15;
#pragma unroll
      for (int r = 0; r < 4; r++) {
        float v = acc[i][j][r];
        if (F32OUT) ((float*)C)[(size_t)(mb + r) * N + nn] = v;
        else        ((u16*)C)[(size_t)(mb + r) * N + nn]  = f2b(v);
      }
    }
  }
}

// ---------------- RMSNorm + RoPE + layout repack (fused-QKV input) ----------------
__global__ __launch_bounds__(256) void k_normrope(const u16* __restrict__ qkv,
                                                  const float* __restrict__ rms_w,
                                                  const int* __restrict__ pos_arr,
                                                  u16* __restrict__ qq,
                                                  u16* __restrict__ kko,
                                                  u16* __restrict__ vto) {
  int idx = blockIdx.x;            // b*SQ + s
  int b = idx >> 11, s = idx & 2047;
  int t = threadIdx.x;
  __shared__ float part[256];
  __shared__ float rstdq[16], rstdk[8];
  __shared__ float lcos[64], lsin[64];
  float pos = (float)pos_arr[s];
  if (t < 64) {
    float ang = pos * exp2f(-0.20762050593046f * (float)t);
    float sn, cs;
    sincosf(ang, &sn, &cs);
    lcos[t] = cs; lsin[t] = sn;
  }
  const u16* qr = qkv + (size_t)idx * 4096;
  const u16* kr = qr + 2048;
  const u16* vr = qr + 3072;
  // ---- Q ----
  int h = t & 15, ch = t >> 4;
  float qv[8]; float ss = 0.f;
#pragma unroll
  for (int j = 0; j < 8; j++) {
    float v = b2f(qr[(ch * 8 + j) * 16 + h]);
    qv[j] = v; ss += v * v;
  }
  part[t] = ss;
  __syncthreads();
  if (t < 16) {
    float tot = 0.f;
#pragma unroll
    for (int c = 0; c < 16; c++) tot += part[c * 16 + t];
    rstdq[t] = rsqrtf(tot * (1.f / 128.f) + 1e-6f);
  }
  __syncthreads();
  {
    float rs = rstdq[h];
    s8v ov;
#pragma unroll
    for (int p = 0; p < 4; p++) {
      int d0 = ch * 8 + p * 2;
      float v0 = qv[p * 2]     * rs * rms_w[d0];
      float v1 = qv[p * 2 + 1] * rs * rms_w[d0 + 1];
      float cs = lcos[d0 >> 1], sn = lsin[d0 >> 1];
      ov[p * 2]     = (short)f2b((v0 * cs - v1 * sn) * 0.08838834764831845f);
      ov[p * 2 + 1] = (short)f2b((v0 * sn + v1 * cs) * 0.08838834764831845f);
    }
    *(s8v*)(qq + ((size_t)(b * 16 + h) * SQ + s) * HD_ + ch * 8) = ov;
  }
  __syncthreads();
  // ---- K/V (threads < 128) ----
  int kv = t & 7, ch2 = t >> 3;
  float kvs[8]; float ssk = 0.f;
  if (t < 128) {
#pragma unroll
    for (int j = 0; j < 8; j++) {
      float v = b2f(kr[(ch2 * 8 + j) * 8 + kv]);
      kvs[j] = v; ssk += v * v;
    }
    part[t] = ssk;
  }
  __syncthreads();
  if (t < 8) {
    float tot = 0.f;
#pragma unroll
    for (int c = 0; c < 16; c++) tot += part[c * 8 + t];
    rstdk[t] = rsqrtf(tot * (1.f / 128.f) + 1e-6f);
  }
  __syncthreads();
  if (t < 128) {
    float rs = rstdk[kv];
    s8v ov;
#pragma unroll
    for (int p = 0; p < 4; p++) {
      int d0 = ch2 * 8 + p * 2;
      float v0 = kvs[p * 2]     * rs * rms_w[d0];
      float v1 = kvs[p * 2 + 1] * rs * rms_w[d0 + 1];
      float cs = lcos[d0 >> 1], sn = lsin[d0 >> 1];
      ov[p * 2]     = (short)f2b(v0 * cs - v1 * sn);
      ov[p * 2 + 1] = (short)f2b(v0 * sn + v1 * cs);
    }
    *(s8v*)(kko + ((size_t)(b * 8 + kv) * SQ + s) * HD_ + ch2 * 8) = ov;
#pragma unroll
    for (int j = 0; j < 8; j++) {
      int d = ch2 * 8 + j;
      vto[((size_t)(b * 8 + kv) * HD_ + d) * SQ + s] = vr[d * 8 + kv];
    }
  }
}

// ---------------- causal flash attention v5: t-split waves + LDS merge ----------
// 64 Q rows/block (2 pairs x 32 rows). Each pair = 2 waves (A,B) splitting the
// t-range; flash-combine through LDS at the end. Inner loop = v4's (swapped
// QK^T, in-register softmax, shfl P-exchange, O^T accum).
__global__ __launch_bounds__(256, 4) void k_attn(const u16* __restrict__ qq,
                                                 const u16* __restrict__ kk,
                                                 const u16* __restrict__ vt,
                                                 u16* __restrict__ ctx) {
  const int tile = (blockIdx.z == 1) ? (31 - (int)blockIdx.x) : (int)blockIdx.x;
  const int s0 = tile * 64;
  const int h  = blockIdx.y;
  const int b  = blockIdx.z;
  const int kvh = h >> 1;
  const int tid = threadIdx.x, lane = tid & 63, w = tid >> 6;
  const int pair = w >> 1;          // 0: rows [s0,s0+32), 1: [s0+32,s0+64)
  const int half = w & 1;           // 0 = A (first t-half, merger), 1 = B
  const int l15 = lane & 15, l4 = lane >> 4;
  const u16* qbase = qq + (size_t)(b * 16 + h) * SQ * HD_;
  const u16* kbase = kk + (size_t)(b * 8 + kvh) * SQ * HD_;
  const u16* vbase = vt + (size_t)(b * 8 + kvh) * HD_ * SQ;
  const int swp = s0 + pair * 32;
  const int bound = swp + 32;
  const int nA = (bound >> 5) >> 1;
  const int tstart = half ? nA * 32 : 0;
  const int tend   = half ? bound : nA * 32;

  __shared__ f4v  moo[2][2][8][64];    // [pair][g][dd][lane]  32 KB
  __shared__ float mml[2][2][2][64];   // [pair][g][{m,l}][lane] 4 KB

  s8v qf[2][4];
#pragma unroll
  for (int g = 0; g < 2; g++)
#pragma unroll
    for (int c = 0; c < 4; c++)
      qf[g][c] = *(const s8v*)(qbase + (size_t)(swp + g * 16 + l15) * HD_ + c * 32 + l4 * 8);

  f4v o[2][8] = {};          // O^T: d = dd*16 + l4*4 + r, s = g*16 + l15
  float m2[2] = {-1e30f, -1e30f};
  float l2[2] = {0.f, 0.f};

  const int src1 = ((l4 & 1) << 5) + l15;   // P-exchange source lanes
  const int src2 = src1 + 16;
  const bool lo = (l4 < 2);

  if (tstart < tend) {
    s8v kf[2][4], vf[8];
#pragma unroll
    for (int tt = 0; tt < 2; tt++)
#pragma unroll
      for (int c = 0; c < 4; c++)
        kf[tt][c] = *(const s8v*)(kbase + (size_t)(tstart + tt * 16 + l15) * HD_ + c * 32 + l4 * 8);
#pragma unroll
    for (int dd = 0; dd < 8; dd++)
      vf[dd] = *(const s8v*)(vbase + (size_t)(dd * 16 + l15) * SQ + tstart + l4 * 8);

    for (int t0 = tstart; t0 < tend; t0 += 32) {
      // swapped QK^T: sc[tt][g] = S^T tile (row=t, col=s)
      f4v sc[2][2] = {};
      __builtin_amdgcn_s_setprio(1);
#pragma unroll
      for (int tt = 0; tt < 2; tt++)
#pragma unroll
        for (int g = 0; g < 2; g++)
#pragma unroll
          for (int c = 0; c < 4; c++)
            sc[tt][g] = __builtin_amdgcn_mfma_f32_16x16x32_bf16(kf[tt][c], qf[g][c], sc[tt][g], 0, 0, 0);
      __builtin_amdgcn_s_setprio(0);
      // reload kf for next tile (hides under softmax + PV)
      const int tn = (t0 + 32 < tend) ? (t0 + 32) : tstart;
#pragma unroll
      for (int tt = 0; tt < 2; tt++)
#pragma unroll
        for (int c = 0; c < 4; c++)
          kf[tt][c] = *(const s8v*)(kbase + (size_t)(tn + tt * 16 + l15) * HD_ + c * 32 + l4 * 8);
      // causal mask — only wave B's diagonal (last) iteration
      if (t0 >= swp) {
#pragma unroll
        for (int tt = 0; tt < 2; tt++)
#pragma unroll
          for (int g = 0; g < 2; g++)
#pragma unroll
            for (int r = 0; r < 4; r++) {
              int tg = t0 + tt * 16 + l4 * 4 + r;
              int sg = swp + g * 16 + l15;
              if (tg > sg) sc[tt][g][r] = -1e30f;
            }
      }
      // softmax (per group; each lane owns one column s)
      s8v pfg[2];
#pragma unroll
      for (int g = 0; g < 2; g++) {
        float mx = fmaxf(fmaxf(fmaxf(sc[0][g][0], sc[0][g][1]), fmaxf(sc[0][g][2], sc[0][g][3])),
                         fmaxf(fmaxf(sc[1][g][0], sc[1][g][1]), fmaxf(sc[1][g][2], sc[1][g][3])));
        mx = fmaxf(mx, __shfl_xor(mx, 16));
        mx = fmaxf(mx, __shfl_xor(mx, 32));
        if (__any(mx > m2[g] + 8.f)) {          // T13 defer-max
          float mn = fmaxf(m2[g], mx);
          float sf = exp2f((m2[g] - mn) * 1.44269504f);
          m2[g] = mn; l2[g] *= sf;
#pragma unroll
          for (int dd = 0; dd < 8; dd++)
#pragma unroll
            for (int r = 0; r < 4; r++) o[g][dd][r] *= sf;
        }
        float p0[4], p1[4], sum = 0.f;
#pragma unroll
        for (int r = 0; r < 4; r++) {
          p0[r] = exp2f((sc[0][g][r] - m2[g]) * 1.44269504f);
          p1[r] = exp2f((sc[1][g][r] - m2[g]) * 1.44269504f);
          sum += p0[r] + p1[r];
        }
        sum += __shfl_xor(sum, 16);
        sum += __shfl_xor(sum, 32);
        l2[g] += sum;
        u32 pa = pk2(p0[0], p0[1]), pb = pk2(p0[2], p0[3]);
        u32 pc = pk2(p1[0], p1[1]), pd = pk2(p1[2], p1[3]);
        u32 xa1 = (u32)__shfl((int)pa, src1), xc1 = (u32)__shfl((int)pc, src1);
        u32 xb1 = (u32)__shfl((int)pb, src1), xd1 = (u32)__shfl((int)pd, src1);
        u32 xa2 = (u32)__shfl((int)pa, src2), xc2 = (u32)__shfl((int)pc, src2);
        u32 xb2 = (u32)__shfl((int)pb, src2), xd2 = (u32)__shfl((int)pd, src2);
        u4v fr;
        fr[0] = lo ? xa1 : xc1;
        fr[1] = lo ? xb1 : xd1;
        fr[2] = lo ? xa2 : xc2;
        fr[3] = lo ? xb2 : xd2;
        pfg[g] = __builtin_bit_cast(s8v, fr);
      }
      // PV: O^T += V^T * P
      __builtin_amdgcn_s_setprio(1);
#pragma unroll
      for (int dd = 0; dd < 8; dd++) {
        o[0][dd] = __builtin_amdgcn_mfma_f32_16x16x32_bf16(vf[dd], pfg[0], o[0][dd], 0, 0, 0);
        o[1][dd] = __builtin_amdgcn_mfma_f32_16x16x32_bf16(vf[dd], pfg[1], o[1][dd], 0, 0, 0);
      }
      __builtin_amdgcn_s_setprio(0);
      // reload vf for next tile (hides under next QK + softmax)
#pragma unroll
      for (int dd = 0; dd < 8; dd++)
        vf[dd] = *(const s8v*)(vbase + (size_t)(dd * 16 + l15) * SQ + tn + l4 * 8);
    }
  }

  // ---- flash-combine A/B halves through LDS ----
  if (half) {
#pragma unroll
    for (int g = 0; g < 2; g++) {
#pragma unroll
      for (int dd = 0; dd < 8; dd++) moo[pair][g][dd][lane] = o[g][dd];
      mml[pair][g][0][lane] = m2[g];
      mml[pair][g][1][lane] = l2[g];
    }
  }
  __syncthreads();
  if (!half) {
#pragma unroll
    for (int g = 0; g < 2; g++) {
      float mB = mml[pair][g][0][lane];
      float lB = mml[pair][g][1][lane];
      float mm = fmaxf(m2[g], mB);
      float fA = exp2f((m2[g] - mm) * 1.44269504f);
      float fB = exp2f((mB - mm) * 1.44269504f);
      float inv = 1.f / (l2[g] * fA + lB * fB);
      size_t rowoff = ((size_t)(b * SQ + swp + g * 16 + l15)) * HDIM + h * HD_;
#pragma unroll
      for (int dd = 0; dd < 8; dd++) {
        f4v ob = moo[pair][g][dd][lane];
        float v0 = (o[g][dd][0] * fA + ob[0] * fB) * inv;
        float v1 = (o[g][dd][1] * fA + ob[1] * fB) * inv;
        float v2 = (o[g][dd][2] * fA + ob[2] * fB) * inv;
        float v3 = (o[g][dd][3] * fA + ob[3] * fB) * inv;
        *(u32*)(ctx + rowoff + dd * 16 + l4 * 4)     = pk2(v0, v1);
        *(u32*)(ctx + rowoff + dd * 16 + l4 * 4 + 2) = pk2(v2, v3);
      }
    }
  }
}

extern "C" void kernel_launch(void* const* d_in, const int* in_sizes, int n_in,
                              void* d_out, int out_size, void* d_ws, size_t ws_size,
                              hipStream_t stream) {
  const float* x     = (const float*)d_in[0];
  const float* wq    = (const float*)d_in[1];
  const float* wk    = (const float*)d_in[2];
  const float* wv    = (const float*)d_in[3];
  const float* wo    = (const float*)d_in[4];
  const float* rms_w = (const float*)d_in[5];
  const int*   pos   = (const int*)d_in[6];

  u16* w = (u16*)d_ws;
  u16* xb   = w;                    // 8388608  x bf16 [4096,2048]; later reused as ctx
  u16* wqt  = xb   + 8388608;       // wqt/wkt/wvt contiguous = QKV B^T [4096][2048]
  u16* wkt  = wqt  + 4194304;
  u16* wvt  = wkt  + 2097152;
  u16* wot  = wvt  + 2097152;
  u16* qkvraw = wot + 4194304;      // 16777216 fused QKV GEMM out [4096][4096]
  u16* kkb  = qkvraw + 16777216;    // kk[b,kv,s,d]
  u16* vtb  = kkb  + 4194304;       // vt[b,kv,d,s]
  u16* qqb  = wqt;                  // alias over wqt..wvt (dead after QKV gemm)
  u16* ctxb = xb;                   // alias over xb (dead after gemms)

  k_cast<<<8192, 256, 0, stream>>>(x, xb, 2097152);
  k_transpose4<<<dim3(64, 64, 4), 256, 0, stream>>>(wq, wk, wv, wo, wqt, wkt, wvt, wot);

  // fused QKV projection: [4096,2048] x [2048,4096] -> [4096,4096]
  k_gemm<0><<<dim3(32, 32), 256, 0, stream>>>(xb, wqt, qkvraw, 4096, 4096, 2048);

  k_normrope<<<4096, 256, 0, stream>>>(qkvraw, rms_w, pos, qqb, kkb, vtb);

  k_attn<<<dim3(32, 16, 2), 256, 0, stream>>>(qqb, kkb, vtb, ctxb);

  k_gemm<1><<<dim3(16, 32), 256, 0, stream>>>(ctxb, wot, d_out, 4096, 2048, 2048);
}

// Round 6
// 286.013 us; speedup vs baseline: 2.5348x; 2.5348x over previous
//
#include <hip/hip_runtime.h>
#include <hip/hip_bf16.h>
#include <stdint.h>

typedef unsigned short u16;
typedef uint32_t u32;
typedef __attribute__((ext_vector_type(8))) short s8v;   // 8 bf16 (4 VGPRs)
typedef __attribute__((ext_vector_type(4))) float f4v;   // 4 fp32
typedef __attribute__((ext_vector_type(4))) unsigned int u4v;

#define SQ   2048
#define HDIM 2048
#define HD_  128
#define NH_  16
#define NKV_ 8

__device__ __forceinline__ u16 f2b(float f) {
  uint32_t u = __builtin_bit_cast(uint32_t, f);
  u += 0x7fffu + ((u >> 16) & 1u);
  return (u16)(u >> 16);
}
__device__ __forceinline__ float b2f(u16 v) {
  uint32_t u = ((uint32_t)v) << 16;
  return __builtin_bit_cast(float, u);
}
__device__ __forceinline__ u32 pk2(float lo, float hi) {
  return (u32)f2b(lo) | ((u32)f2b(hi) << 16);
}

// ---------------- cast f32 -> bf16, 4 elems/thread ----------------
__global__ __launch_bounds__(256) void k_cast(const float* __restrict__ in,
                                              u16* __restrict__ out, int n4) {
  int i = blockIdx.x * 256 + threadIdx.x;
  if (i >= n4) return;
  f4v v = *(const f4v*)(in + (size_t)i * 4);
  union { u16 s[4]; uint64_t u; } o;
  o.s[0] = f2b(v[0]); o.s[1] = f2b(v[1]); o.s[2] = f2b(v[2]); o.s[3] = f2b(v[3]);
  *(uint64_t*)(out + (size_t)i * 4) = o.u;
}

// ---------------- fused transpose+cast for all 4 weights ----------------
__global__ __launch_bounds__(256) void k_transpose4(const float* __restrict__ wq,
                                                    const float* __restrict__ wk,
                                                    const float* __restrict__ wv,
                                                    const float* __restrict__ wo,
                                                    u16* __restrict__ wqt,
                                                    u16* __restrict__ wkt,
                                                    u16* __restrict__ wvt,
                                                    u16* __restrict__ wot) {
  const int z = blockIdx.z;
  const float* in = (z == 0) ? wq : (z == 1) ? wk : (z == 2) ? wv : wo;
  u16* out = (z == 0) ? wqt : (z == 1) ? wkt : (z == 2) ? wvt : wot;
  const int cols = (z == 1 || z == 2) ? 1024 : 2048;
  int c0 = blockIdx.x * 32, r0 = blockIdx.y * 32;
  if (c0 >= cols) return;
  __shared__ float tile[32][33];
  int tx = threadIdx.x & 31, ty = threadIdx.x >> 5;
#pragma unroll
  for (int i = 0; i < 32; i += 8)
    tile[ty + i][tx] = in[(size_t)(r0 + ty + i) * cols + c0 + tx];
  __syncthreads();
#pragma unroll
  for (int i = 0; i < 32; i += 8)
    out[(size_t)(c0 + ty + i) * 2048 + r0 + tx] = f2b(tile[tx][ty + i]);
}

// ---------------- bf16 GEMM: C[M,N] = A[M,K] * Bt[N,K]^T ----------------
template <int F32OUT>
__global__ __launch_bounds__(256) void k_gemm(const u16* __restrict__ A,
                                              const u16* __restrict__ Bt,
                                              void* __restrict__ C,
                                              int M, int N, int K) {
  __shared__ __align__(16) u16 As[128 * 64];
  __shared__ __align__(16) u16 Bs[128 * 64];
  const int tid = threadIdx.x;
  const int lane = tid & 63, wvi = tid >> 6;
  const int wm = wvi >> 1, wn = wvi & 1;
  const int l15 = lane & 15, l4 = lane >> 4;
  const int m0 = blockIdx.y * 128, n0 = blockIdx.x * 128;
  auto* As3 = (__attribute__((address_space(3))) char*)As;
  auto* Bs3 = (__attribute__((address_space(3))) char*)Bs;
  int srow[4], soff[4];
#pragma unroll
  for (int i = 0; i < 4; i++) {
    int slot = wvi * 4096 + i * 1024 + lane * 16;
    int r = slot >> 7;
    int gc = ((slot >> 4) & 7) ^ (r & 7);
    srow[i] = r; soff[i] = gc * 16;
  }
  f4v acc[4][4] = {};
  for (int k0 = 0; k0 < K; k0 += 64) {
#pragma unroll
    for (int i = 0; i < 4; i++) {
      const char* gA = (const char*)(A + (size_t)(m0 + srow[i]) * K + k0) + soff[i];
      const char* gB = (const char*)(Bt + (size_t)(n0 + srow[i]) * K + k0) + soff[i];
      __builtin_amdgcn_global_load_lds((__attribute__((address_space(1))) void*)gA,
                                       (__attribute__((address_space(3))) void*)(As3 + wvi * 4096 + i * 1024),
                                       16, 0, 0);
      __builtin_amdgcn_global_load_lds((__attribute__((address_space(1))) void*)gB,
                                       (__attribute__((address_space(3))) void*)(Bs3 + wvi * 4096 + i * 1024),
                                       16, 0, 0);
    }
    __syncthreads();
#pragma unroll
    for (int kk = 0; kk < 2; kk++) {
      s8v af[4], bf[4];
#pragma unroll
      for (int i = 0; i < 4; i++) {
        int ra = wm * 64 + i * 16 + l15;
        af[i] = *(const s8v*)((const char*)As + ra * 128 +
                              ((kk * 64 + l4 * 16) ^ ((ra & 7) << 4)));
        int rb = wn * 64 + i * 16 + l15;
        bf[i] = *(const s8v*)((const char*)Bs + rb * 128 +
                              ((kk * 64 + l4 * 16) ^ ((rb & 7) << 4)));
      }
#pragma unroll
      for (int i = 0; i < 4; i++)
#pragma unroll
        for (int j = 0; j < 4; j++)
          acc[i][j] = __builtin_amdgcn_mfma_f32_16x16x32_bf16(af[i], bf[j], acc[i][j], 0, 0, 0);
    }
    __syncthreads();
  }
#pragma unroll
  for (int i = 0; i < 4; i++) {
#pragma unroll
    for (int j = 0; j < 4; j++) {
      int mb = m0 + wm * 64 + i * 16 + l4 * 4;
      int nn = n0 + wn * 64 + j * 16 + l15;
#pragma unroll
      for (int r = 0; r < 4; r++) {
        float v = acc[i][j][r];
        if (F32OUT) ((float*)C)[(size_t)(mb + r) * N + nn] = v;
        else        ((u16*)C)[(size_t)(mb + r) * N + nn]  = f2b(v);
      }
    }
  }
}

// ---------------- RMSNorm + RoPE + layout repack (fused-QKV input) ----------------
__global__ __launch_bounds__(256) void k_normrope(const u16* __restrict__ qkv,
                                                  const float* __restrict__ rms_w,
                                                  const int* __restrict__ pos_arr,
                                                  u16* __restrict__ qq,
                                                  u16* __restrict__ kko,
                                                  u16* __restrict__ vto) {
  int idx = blockIdx.x;            // b*SQ + s
  int b = idx >> 11, s = idx & 2047;
  int t = threadIdx.x;
  __shared__ float part[256];
  __shared__ float rstdq[16], rstdk[8];
  __shared__ float lcos[64], lsin[64];
  float pos = (float)pos_arr[s];
  if (t < 64) {
    float ang = pos * exp2f(-0.20762050593046f * (float)t);
    float sn, cs;
    sincosf(ang, &sn, &cs);
    lcos[t] = cs; lsin[t] = sn;
  }
  const u16* qr = qkv + (size_t)idx * 4096;
  const u16* kr = qr + 2048;
  const u16* vr = qr + 3072;
  // ---- Q ----
  int h = t & 15, ch = t >> 4;
  float qv[8]; float ss = 0.f;
#pragma unroll
  for (int j = 0; j < 8; j++) {
    float v = b2f(qr[(ch * 8 + j) * 16 + h]);
    qv[j] = v; ss += v * v;
  }
  part[t] = ss;
  __syncthreads();
  if (t < 16) {
    float tot = 0.f;
#pragma unroll
    for (int c = 0; c < 16; c++) tot += part[c * 16 + t];
    rstdq[t] = rsqrtf(tot * (1.f / 128.f) + 1e-6f);
  }
  __syncthreads();
  {
    float rs = rstdq[h];
    s8v ov;
#pragma unroll
    for (int p = 0; p < 4; p++) {
      int d0 = ch * 8 + p * 2;
      float v0 = qv[p * 2]     * rs * rms_w[d0];
      float v1 = qv[p * 2 + 1] * rs * rms_w[d0 + 1];
      float cs = lcos[d0 >> 1], sn = lsin[d0 >> 1];
      ov[p * 2]     = (short)f2b((v0 * cs - v1 * sn) * 0.08838834764831845f);
      ov[p * 2 + 1] = (short)f2b((v0 * sn + v1 * cs) * 0.08838834764831845f);
    }
    *(s8v*)(qq + ((size_t)(b * 16 + h) * SQ + s) * HD_ + ch * 8) = ov;
  }
  __syncthreads();
  // ---- K/V (threads < 128) ----
  int kv = t & 7, ch2 = t >> 3;
  float kvs[8]; float ssk = 0.f;
  if (t < 128) {
#pragma unroll
    for (int j = 0; j < 8; j++) {
      float v = b2f(kr[(ch2 * 8 + j) * 8 + kv]);
      kvs[j] = v; ssk += v * v;
    }
    part[t] = ssk;
  }
  __syncthreads();
  if (t < 8) {
    float tot = 0.f;
#pragma unroll
    for (int c = 0; c < 16; c++) tot += part[c * 8 + t];
    rstdk[t] = rsqrtf(tot * (1.f / 128.f) + 1e-6f);
  }
  __syncthreads();
  if (t < 128) {
    float rs = rstdk[kv];
    s8v ov;
#pragma unroll
    for (int p = 0; p < 4; p++) {
      int d0 = ch2 * 8 + p * 2;
      float v0 = kvs[p * 2]     * rs * rms_w[d0];
      float v1 = kvs[p * 2 + 1] * rs * rms_w[d0 + 1];
      float cs = lcos[d0 >> 1], sn = lsin[d0 >> 1];
      ov[p * 2]     = (short)f2b(v0 * cs - v1 * sn);
      ov[p * 2 + 1] = (short)f2b(v0 * sn + v1 * cs);
    }
    *(s8v*)(kko + ((size_t)(b * 8 + kv) * SQ + s) * HD_ + ch2 * 8) = ov;
#pragma unroll
    for (int j = 0; j < 8; j++) {
      int d = ch2 * 8 + j;
      vto[((size_t)(b * 8 + kv) * HD_ + d) * SQ + s] = vr[d * 8 + kv];
    }
  }
}

// ---------------- causal flash attention v6: block-shared K/V in LDS ----------
// 64 Q rows/block, 4 waves x 16 rows, KVBLK=32, K/V double-buffered in LDS via
// global_load_lds (rule-21 swizzle). 2-phase stage-ahead loop, one barrier/tile.
// Inner math = v4 (swapped QK^T, in-register softmax, shfl P-exchange, O^T).
__global__ __launch_bounds__(256, 3) void k_attn(const u16* __restrict__ qq,
                                                 const u16* __restrict__ kk,
                                                 const u16* __restrict__ vt,
                                                 u16* __restrict__ ctx) {
  const int tile = (blockIdx.z == 1) ? (31 - (int)blockIdx.x) : (int)blockIdx.x;
  const int s0 = tile * 64;
  const int h  = blockIdx.y;
  const int b  = blockIdx.z;
  const int kvh = h >> 1;
  const int tid = threadIdx.x, lane = tid & 63, w = tid >> 6;
  const int l15 = lane & 15, l4 = lane >> 4;
  __shared__ __align__(16) u16 Kl[2][32 * 128];   // [buf][t][d]  8KB each
  __shared__ __align__(16) u16 Vl[2][128 * 32];   // [buf][d][t]  8KB each
  auto* K3 = (__attribute__((address_space(3))) char*)&Kl[0][0];
  auto* V3 = (__attribute__((address_space(3))) char*)&Vl[0][0];
  const u16* qbase = qq + (size_t)(b * 16 + h) * SQ * HD_;
  const u16* kbase = kk + (size_t)(b * 8 + kvh) * SQ * HD_;
  const u16* vbase = vt + (size_t)(b * 8 + kvh) * HD_ * SQ;
  const int swp = s0 + w * 16;

  // staging source maps (linear LDS dest; inverse-swizzled global source)
  int ksr[2], kso[2], vsr[2], vso[2];
#pragma unroll
  for (int j = 0; j < 2; j++) {
    int s = j * 256 + tid;
    ksr[j] = s >> 4;                                  // K row 0..31
    kso[j] = (((s & 15) ^ (ksr[j] & 7)) << 4);        // byte off in 256B row
    vsr[j] = s >> 2;                                  // V row (d) 0..127
    vso[j] = (((s & 3) ^ ((vsr[j] >> 1) & 3)) << 4);  // byte off in 64B row
  }

  s8v qf[4];
#pragma unroll
  for (int c = 0; c < 4; c++)
    qf[c] = *(const s8v*)(qbase + (size_t)(swp + l15) * HD_ + c * 32 + l4 * 8);

  f4v o[8] = {};             // O^T: d = dd*16 + l4*4 + r, s = l15
  float m2 = -1e30f, l2 = 0.f;

  const int src1 = ((l4 & 1) << 5) + l15;
  const int src2 = src1 + 16;
  const bool lo = (l4 < 2);

  const int blockBound = s0 + 64;
  const int mybound = swp + 16;

#define STAGE(buf, t0s)                                                          \
  do {                                                                           \
    _Pragma("unroll")                                                            \
    for (int j = 0; j < 2; j++) {                                                \
      const char* gk = (const char*)(kbase + (size_t)((t0s) + ksr[j]) * HD_) + kso[j]; \
      __builtin_amdgcn_global_load_lds(                                          \
          (const __attribute__((address_space(1))) void*)gk,                     \
          (__attribute__((address_space(3))) void*)(K3 + (buf) * 8192 + j * 4096 + w * 1024 + (lane << 4)), \
          16, 0, 0);                                                             \
    }                                                                            \
    _Pragma("unroll")                                                            \
    for (int j = 0; j < 2; j++) {                                                \
      const char* gv = (const char*)(vbase + (size_t)vsr[j] * SQ + (t0s)) + vso[j]; \
      __builtin_amdgcn_global_load_lds(                                          \
          (const __attribute__((address_space(1))) void*)gv,                     \
          (__attribute__((address_space(3))) void*)(V3 + (buf) * 8192 + j * 4096 + w * 1024 + (lane << 4)), \
          16, 0, 0);                                                             \
    }                                                                            \
  } while (0)

  STAGE(0, 0);
  __syncthreads();
  int cur = 0;
  for (int t0 = 0; t0 < blockBound; t0 += 32) {
    if (t0 + 32 < blockBound) STAGE(cur ^ 1, t0 + 32);
    if (t0 < mybound) {
      const char* kbuf = (const char*)&Kl[cur][0];
      const char* vbuf = (const char*)&Vl[cur][0];
      // K fragments from LDS (swizzled reads)
      s8v kf[2][4];
#pragma unroll
      for (int tt = 0; tt < 2; tt++) {
        int row = tt * 16 + l15;
#pragma unroll
        for (int c = 0; c < 4; c++)
          kf[tt][c] = *(const s8v*)(kbuf + row * 256 + ((((c << 2) + l4) ^ (row & 7)) << 4));
      }
      // swapped QK^T: sc[tt] = S^T (row=t, col=s)
      f4v sc[2] = {};
      __builtin_amdgcn_s_setprio(1);
#pragma unroll
      for (int tt = 0; tt < 2; tt++)
#pragma unroll
        for (int c = 0; c < 4; c++)
          sc[tt] = __builtin_amdgcn_mfma_f32_16x16x32_bf16(kf[tt][c], qf[c], sc[tt], 0, 0, 0);
      __builtin_amdgcn_s_setprio(0);
      // causal mask (diagonal tiles only)
      if (t0 + 31 >= swp) {
#pragma unroll
        for (int tt = 0; tt < 2; tt++)
#pragma unroll
          for (int r = 0; r < 4; r++) {
            int tg = t0 + tt * 16 + l4 * 4 + r;
            int sg = swp + l15;
            if (tg > sg) sc[tt][r] = -1e30f;
          }
      }
      // in-register online softmax (lane owns column s)
      float mx = fmaxf(fmaxf(fmaxf(sc[0][0], sc[0][1]), fmaxf(sc[0][2], sc[0][3])),
                       fmaxf(fmaxf(sc[1][0], sc[1][1]), fmaxf(sc[1][2], sc[1][3])));
      mx = fmaxf(mx, __shfl_xor(mx, 16));
      mx = fmaxf(mx, __shfl_xor(mx, 32));
      if (__any(mx > m2 + 8.f)) {              // T13 defer-max
        float mn = fmaxf(m2, mx);
        float sf = exp2f((m2 - mn) * 1.44269504f);
        m2 = mn; l2 *= sf;
#pragma unroll
        for (int dd = 0; dd < 8; dd++)
#pragma unroll
          for (int r = 0; r < 4; r++) o[dd][r] *= sf;
      }
      float p0[4], p1[4], sum = 0.f;
#pragma unroll
      for (int r = 0; r < 4; r++) {
        p0[r] = exp2f((sc[0][r] - m2) * 1.44269504f);
        p1[r] = exp2f((sc[1][r] - m2) * 1.44269504f);
        sum += p0[r] + p1[r];
      }
      sum += __shfl_xor(sum, 16);
      sum += __shfl_xor(sum, 32);
      l2 += sum;
      // P exchange -> PV B-fragment
      u32 pa = pk2(p0[0], p0[1]), pb = pk2(p0[2], p0[3]);
      u32 pc = pk2(p1[0], p1[1]), pd = pk2(p1[2], p1[3]);
      u32 xa1 = (u32)__shfl((int)pa, src1), xc1 = (u32)__shfl((int)pc, src1);
      u32 xb1 = (u32)__shfl((int)pb, src1), xd1 = (u32)__shfl((int)pd, src1);
      u32 xa2 = (u32)__shfl((int)pa, src2), xc2 = (u32)__shfl((int)pc, src2);
      u32 xb2 = (u32)__shfl((int)pb, src2), xd2 = (u32)__shfl((int)pd, src2);
      u4v fr;
      fr[0] = lo ? xa1 : xc1;
      fr[1] = lo ? xb1 : xd1;
      fr[2] = lo ? xa2 : xc2;
      fr[3] = lo ? xb2 : xd2;
      s8v pf = __builtin_bit_cast(s8v, fr);
      // V fragments from LDS + PV
      __builtin_amdgcn_s_setprio(1);
#pragma unroll
      for (int dd = 0; dd < 8; dd++) {
        int row = dd * 16 + l15;
        s8v vf = *(const s8v*)(vbuf + row * 64 + ((l4 ^ ((row >> 1) & 3)) << 4));
        o[dd] = __builtin_amdgcn_mfma_f32_16x16x32_bf16(vf, pf, o[dd], 0, 0, 0);
      }
      __builtin_amdgcn_s_setprio(0);
    }
    __syncthreads();
    cur ^= 1;
  }
#undef STAGE
  // epilogue: lane owns column s = swp + l15; d = dd*16 + l4*4 + r
  float inv = 1.f / l2;
  size_t rowoff = ((size_t)(b * SQ + swp + l15)) * HDIM + h * HD_;
#pragma unroll
  for (int dd = 0; dd < 8; dd++) {
    *(u32*)(ctx + rowoff + dd * 16 + l4 * 4)     = pk2(o[dd][0] * inv, o[dd][1] * inv);
    *(u32*)(ctx + rowoff + dd * 16 + l4 * 4 + 2) = pk2(o[dd][2] * inv, o[dd][3] * inv);
  }
}

extern "C" void kernel_launch(void* const* d_in, const int* in_sizes, int n_in,
                              void* d_out, int out_size, void* d_ws, size_t ws_size,
                              hipStream_t stream) {
  const float* x     = (const float*)d_in[0];
  const float* wq    = (const float*)d_in[1];
  const float* wk    = (const float*)d_in[2];
  const float* wv    = (const float*)d_in[3];
  const float* wo    = (const float*)d_in[4];
  const float* rms_w = (const float*)d_in[5];
  const int*   pos   = (const int*)d_in[6];

  u16* w = (u16*)d_ws;
  u16* xb   = w;                    // 8388608  x bf16 [4096,2048]; later reused as ctx
  u16* wqt  = xb   + 8388608;       // wqt/wkt/wvt contiguous = QKV B^T [4096][2048]
  u16* wkt  = wqt  + 4194304;
  u16* wvt  = wkt  + 2097152;
  u16* wot  = wvt  + 2097152;
  u16* qkvraw = wot + 4194304;      // 16777216 fused QKV GEMM out [4096][4096]
  u16* kkb  = qkvraw + 16777216;    // kk[b,kv,s,d]
  u16* vtb  = kkb  + 4194304;       // vt[b,kv,d,s]
  u16* qqb  = wqt;                  // alias over wqt..wvt (dead after QKV gemm)
  u16* ctxb = xb;                   // alias over xb (dead after gemms)

  k_cast<<<8192, 256, 0, stream>>>(x, xb, 2097152);
  k_transpose4<<<dim3(64, 64, 4), 256, 0, stream>>>(wq, wk, wv, wo, wqt, wkt, wvt, wot);

  // fused QKV projection: [4096,2048] x [2048,4096] -> [4096,4096]
  k_gemm<0><<<dim3(32, 32), 256, 0, stream>>>(xb, wqt, qkvraw, 4096, 4096, 2048);

  k_normrope<<<4096, 256, 0, stream>>>(qkvraw, rms_w, pos, qqb, kkb, vtb);

  k_attn<<<dim3(32, 16, 2), 256, 0, stream>>>(qqb, kkb, vtb, ctxb);

  k_gemm<1><<<dim3(16, 32), 256, 0, stream>>>(ctxb, wot, d_out, 4096, 2048, 2048);
}

// Round 7
// 270.878 us; speedup vs baseline: 2.6765x; 1.0559x over previous
//
#include <hip/hip_runtime.h>
#include <hip/hip_bf16.h>
#include <stdint.h>

typedef unsigned short u16;
typedef uint32_t u32;
typedef __attribute__((ext_vector_type(8))) short s8v;   // 8 bf16 (4 VGPRs)
typedef __attribute__((ext_vector_type(4))) float f4v;   // 4 fp32
typedef __attribute__((ext_vector_type(4))) unsigned int u4v;

#define SQ   2048
#define HDIM 2048
#define HD_  128
#define NH_  16
#define NKV_ 8

__device__ __forceinline__ u16 f2b(float f) {
  uint32_t u = __builtin_bit_cast(uint32_t, f);
  u += 0x7fffu + ((u >> 16) & 1u);
  return (u16)(u >> 16);
}
__device__ __forceinline__ float b2f(u16 v) {
  uint32_t u = ((uint32_t)v) << 16;
  return __builtin_bit_cast(float, u);
}
__device__ __forceinline__ u32 pk2(float lo, float hi) {
  return (u32)f2b(lo) | ((u32)f2b(hi) << 16);
}
// hardware packed f32x2 -> bf16x2 (RNE), single VALU op
__device__ __forceinline__ u32 cvtpk(float lo, float hi) {
  u32 r;
  asm("v_cvt_pk_bf16_f32 %0, %1, %2" : "=v"(r) : "v"(lo), "v"(hi));
  return r;
}

// ---------------- cast f32 -> bf16, 4 elems/thread ----------------
__global__ __launch_bounds__(256) void k_cast(const float* __restrict__ in,
                                              u16* __restrict__ out, int n4) {
  int i = blockIdx.x * 256 + threadIdx.x;
  if (i >= n4) return;
  f4v v = *(const f4v*)(in + (size_t)i * 4);
  union { u16 s[4]; uint64_t u; } o;
  o.s[0] = f2b(v[0]); o.s[1] = f2b(v[1]); o.s[2] = f2b(v[2]); o.s[3] = f2b(v[3]);
  *(uint64_t*)(out + (size_t)i * 4) = o.u;
}

// ---------------- fused transpose+cast for all 4 weights ----------------
__global__ __launch_bounds__(256) void k_transpose4(const float* __restrict__ wq,
                                                    const float* __restrict__ wk,
                                                    const float* __restrict__ wv,
                                                    const float* __restrict__ wo,
                                                    u16* __restrict__ wqt,
                                                    u16* __restrict__ wkt,
                                                    u16* __restrict__ wvt,
                                                    u16* __restrict__ wot) {
  const int z = blockIdx.z;
  const float* in = (z == 0) ? wq : (z == 1) ? wk : (z == 2) ? wv : wo;
  u16* out = (z == 0) ? wqt : (z == 1) ? wkt : (z == 2) ? wvt : wot;
  const int cols = (z == 1 || z == 2) ? 1024 : 2048;
  int c0 = blockIdx.x * 32, r0 = blockIdx.y * 32;
  if (c0 >= cols) return;
  __shared__ float tile[32][33];
  int tx = threadIdx.x & 31, ty = threadIdx.x >> 5;
#pragma unroll
  for (int i = 0; i < 32; i += 8)
    tile[ty + i][tx] = in[(size_t)(r0 + ty + i) * cols + c0 + tx];
  __syncthreads();
#pragma unroll
  for (int i = 0; i < 32; i += 8)
    out[(size_t)(c0 + ty + i) * 2048 + r0 + tx] = f2b(tile[tx][ty + i]);
}

// ---------------- bf16 GEMM: C[M,N] = A[M,K] * Bt[N,K]^T ----------------
template <int F32OUT>
__global__ __launch_bounds__(256) void k_gemm(const u16* __restrict__ A,
                                              const u16* __restrict__ Bt,
                                              void* __restrict__ C,
                                              int M, int N, int K) {
  __shared__ __align__(16) u16 As[128 * 64];
  __shared__ __align__(16) u16 Bs[128 * 64];
  const int tid = threadIdx.x;
  const int lane = tid & 63, wvi = tid >> 6;
  const int wm = wvi >> 1, wn = wvi & 1;
  const int l15 = lane & 15, l4 = lane >> 4;
  const int m0 = blockIdx.y * 128, n0 = blockIdx.x * 128;
  auto* As3 = (__attribute__((address_space(3))) char*)As;
  auto* Bs3 = (__attribute__((address_space(3))) char*)Bs;
  int srow[4], soff[4];
#pragma unroll
  for (int i = 0; i < 4; i++) {
    int slot = wvi * 4096 + i * 1024 + lane * 16;
    int r = slot >> 7;
    int gc = ((slot >> 4) & 7) ^ (r & 7);
    srow[i] = r; soff[i] = gc * 16;
  }
  f4v acc[4][4] = {};
  for (int k0 = 0; k0 < K; k0 += 64) {
#pragma unroll
    for (int i = 0; i < 4; i++) {
      const char* gA = (const char*)(A + (size_t)(m0 + srow[i]) * K + k0) + soff[i];
      const char* gB = (const char*)(Bt + (size_t)(n0 + srow[i]) * K + k0) + soff[i];
      __builtin_amdgcn_global_load_lds((__attribute__((address_space(1))) void*)gA,
                                       (__attribute__((address_space(3))) void*)(As3 + wvi * 4096 + i * 1024),
                                       16, 0, 0);
      __builtin_amdgcn_global_load_lds((__attribute__((address_space(1))) void*)gB,
                                       (__attribute__((address_space(3))) void*)(Bs3 + wvi * 4096 + i * 1024),
                                       16, 0, 0);
    }
    __syncthreads();
#pragma unroll
    for (int kk = 0; kk < 2; kk++) {
      s8v af[4], bf[4];
#pragma unroll
      for (int i = 0; i < 4; i++) {
        int ra = wm * 64 + i * 16 + l15;
        af[i] = *(const s8v*)((const char*)As + ra * 128 +
                              ((kk * 64 + l4 * 16) ^ ((ra & 7) << 4)));
        int rb = wn * 64 + i * 16 + l15;
        bf[i] = *(const s8v*)((const char*)Bs + rb * 128 +
                              ((kk * 64 + l4 * 16) ^ ((rb & 7) << 4)));
      }
#pragma unroll
      for (int i = 0; i < 4; i++)
#pragma unroll
        for (int j = 0; j < 4; j++)
          acc[i][j] = __builtin_amdgcn_mfma_f32_16x16x32_bf16(af[i], bf[j], acc[i][j], 0, 0, 0);
    }
    __syncthreads();
  }
#pragma unroll
  for (int i = 0; i < 4; i++) {
#pragma unroll
    for (int j = 0; j < 4; j++) {
      int mb = m0 + wm * 64 + i * 16 + l4 * 4;
      int nn = n0 + wn * 64 + j * 16 + l15;
#pragma unroll
      for (int r = 0; r < 4; r++) {
        float v = acc[i][j][r];
        if (F32OUT) ((float*)C)[(size_t)(mb + r) * N + nn] = v;
        else        ((u16*)C)[(size_t)(mb + r) * N + nn]  = f2b(v);
      }
    }
  }
}

// ---------------- RMSNorm + RoPE + layout repack (fused-QKV input) ----------------
__global__ __launch_bounds__(256) void k_normrope(const u16* __restrict__ qkv,
                                                  const float* __restrict__ rms_w,
                                                  const int* __restrict__ pos_arr,
                                                  u16* __restrict__ qq,
                                                  u16* __restrict__ kko,
                                                  u16* __restrict__ vto) {
  int idx = blockIdx.x;            // b*SQ + s
  int b = idx >> 11, s = idx & 2047;
  int t = threadIdx.x;
  __shared__ float part[256];
  __shared__ float rstdq[16], rstdk[8];
  __shared__ float lcos[64], lsin[64];
  float pos = (float)pos_arr[s];
  if (t < 64) {
    float ang = pos * exp2f(-0.20762050593046f * (float)t);
    float sn, cs;
    sincosf(ang, &sn, &cs);
    lcos[t] = cs; lsin[t] = sn;
  }
  const u16* qr = qkv + (size_t)idx * 4096;
  const u16* kr = qr + 2048;
  const u16* vr = qr + 3072;
  // ---- Q ----
  int h = t & 15, ch = t >> 4;
  float qv[8]; float ss = 0.f;
#pragma unroll
  for (int j = 0; j < 8; j++) {
    float v = b2f(qr[(ch * 8 + j) * 16 + h]);
    qv[j] = v; ss += v * v;
  }
  part[t] = ss;
  __syncthreads();
  if (t < 16) {
    float tot = 0.f;
#pragma unroll
    for (int c = 0; c < 16; c++) tot += part[c * 16 + t];
    rstdq[t] = rsqrtf(tot * (1.f / 128.f) + 1e-6f);
  }
  __syncthreads();
  {
    float rs = rstdq[h];
    s8v ov;
#pragma unroll
    for (int p = 0; p < 4; p++) {
      int d0 = ch * 8 + p * 2;
      float v0 = qv[p * 2]     * rs * rms_w[d0];
      float v1 = qv[p * 2 + 1] * rs * rms_w[d0 + 1];
      float cs = lcos[d0 >> 1], sn = lsin[d0 >> 1];
      ov[p * 2]     = (short)f2b((v0 * cs - v1 * sn) * 0.08838834764831845f);
      ov[p * 2 + 1] = (short)f2b((v0 * sn + v1 * cs) * 0.08838834764831845f);
    }
    *(s8v*)(qq + ((size_t)(b * 16 + h) * SQ + s) * HD_ + ch * 8) = ov;
  }
  __syncthreads();
  // ---- K/V (threads < 128) ----
  int kv = t & 7, ch2 = t >> 3;
  float kvs[8]; float ssk = 0.f;
  if (t < 128) {
#pragma unroll
    for (int j = 0; j < 8; j++) {
      float v = b2f(kr[(ch2 * 8 + j) * 8 + kv]);
      kvs[j] = v; ssk += v * v;
    }
    part[t] = ssk;
  }
  __syncthreads();
  if (t < 8) {
    float tot = 0.f;
#pragma unroll
    for (int c = 0; c < 16; c++) tot += part[c * 8 + t];
    rstdk[t] = rsqrtf(tot * (1.f / 128.f) + 1e-6f);
  }
  __syncthreads();
  if (t < 128) {
    float rs = rstdk[kv];
    s8v ov;
#pragma unroll
    for (int p = 0; p < 4; p++) {
      int d0 = ch2 * 8 + p * 2;
      float v0 = kvs[p * 2]     * rs * rms_w[d0];
      float v1 = kvs[p * 2 + 1] * rs * rms_w[d0 + 1];
      float cs = lcos[d0 >> 1], sn = lsin[d0 >> 1];
      ov[p * 2]     = (short)f2b(v0 * cs - v1 * sn);
      ov[p * 2 + 1] = (short)f2b(v0 * sn + v1 * cs);
    }
    *(s8v*)(kko + ((size_t)(b * 8 + kv) * SQ + s) * HD_ + ch2 * 8) = ov;
#pragma unroll
    for (int j = 0; j < 8; j++) {
      int d = ch2 * 8 + j;
      vto[((size_t)(b * 8 + kv) * HD_ + d) * SQ + s] = vr[d * 8 + kv];
    }
  }
}

// ---------------- causal flash attention v7 ------------------------------------
// 128 Q rows/block, 8 waves x 16 rows, KVBLK=64. K[64][128] + V[128][64] LDS
// double-buffered via global_load_lds (rule-21 swizzle, 128B rows both).
// Raw s_barrier + counted vmcnt(4): stage tile i+2 after post-compute barrier,
// so at tile i's wait the 4 newest outstanding loads are tile i+1's. cvt_pk
// packing; swapped QK^T; in-register softmax; select-after-shuffle P exchange.
__global__ __launch_bounds__(512, 2) void k_attn(const u16* __restrict__ qq,
                                                 const u16* __restrict__ kk,
                                                 const u16* __restrict__ vt,
                                                 u16* __restrict__ ctx) {
  const int tile = (blockIdx.z == 1) ? (15 - (int)blockIdx.x) : (int)blockIdx.x;
  const int s0 = tile * 128;
  const int h  = blockIdx.y;
  const int b  = blockIdx.z;
  const int kvh = h >> 1;
  const int tid = threadIdx.x, lane = tid & 63, w = tid >> 6;
  const int l15 = lane & 15, l4 = lane >> 4;
  __shared__ __align__(16) u16 Kl[2][64 * 128];   // [buf][t][d]  16KB each
  __shared__ __align__(16) u16 Vl[2][128 * 64];   // [buf][d][t]  16KB each
  auto* K3 = (__attribute__((address_space(3))) char*)&Kl[0][0];
  auto* V3 = (__attribute__((address_space(3))) char*)&Vl[0][0];
  const u16* qbase = qq + (size_t)(b * 16 + h) * SQ * HD_;
  const u16* kbase = kk + (size_t)(b * 8 + kvh) * SQ * HD_;
  const u16* vbase = vt + (size_t)(b * 8 + kvh) * HD_ * SQ;
  const int swp = s0 + w * 16;
  const int mybound = swp + 16;
  const int ntiles = 2 * tile + 2;

  // staging source maps (linear LDS dest; inverse-swizzled global source)
  int krow[2], kgo[2], vrow[2], vgo[2];
#pragma unroll
  for (int j = 0; j < 2; j++) {
    int s = j * 8192 + tid * 16;                   // byte slot
    krow[j] = s >> 8;                              // K row (t) 0..63, 256B rows
    kgo[j]  = (((s >> 4) & 15) ^ (krow[j] & 7)) * 8;   // u16 offset in row
    vrow[j] = s >> 7;                              // V row (d) 0..127, 128B rows
    vgo[j]  = (((s >> 4) & 7) ^ (vrow[j] & 7)) * 8;
  }

#define STAGE(buf, t0s)                                                           \
  do {                                                                            \
    _Pragma("unroll")                                                             \
    for (int j = 0; j < 2; j++) {                                                 \
      const u16* gk = kbase + (size_t)((t0s) + krow[j]) * HD_ + kgo[j];           \
      __builtin_amdgcn_global_load_lds(                                           \
          (const __attribute__((address_space(1))) void*)gk,                      \
          (__attribute__((address_space(3))) void*)(K3 + (buf) * 16384 + j * 8192 + tid * 16), \
          16, 0, 0);                                                              \
      const u16* gv = vbase + (size_t)vrow[j] * SQ + (t0s) + vgo[j];              \
      __builtin_amdgcn_global_load_lds(                                           \
          (const __attribute__((address_space(1))) void*)gv,                      \
          (__attribute__((address_space(3))) void*)(V3 + (buf) * 16384 + j * 8192 + tid * 16), \
          16, 0, 0);                                                              \
    }                                                                             \
  } while (0)

  s8v qf[4];
#pragma unroll
  for (int c = 0; c < 4; c++)
    qf[c] = *(const s8v*)(qbase + (size_t)(swp + l15) * HD_ + c * 32 + l4 * 8);

  f4v o[8] = {};             // O^T: d = dd*16 + l4*4 + r, s = l15
  float m2 = -1e30f, l2 = 0.f;

  const int src1 = ((l4 & 1) << 5) + l15;
  const int src2 = src1 + 16;
  const bool selhi = (l4 >> 1) != 0;
  const int swzk = (l15 & 7);            // row&7 == l15&7 for all our LDS rows

  // hoistable swizzled chunk offsets (u16 units)
  int xk[4], xv[2];
#pragma unroll
  for (int c = 0; c < 4; c++) xk[c] = ((c * 4 + l4) ^ swzk) * 8;
#pragma unroll
  for (int ks = 0; ks < 2; ks++) xv[ks] = ((ks * 4 + l4) ^ swzk) * 8;

  STAGE(0, 0);
  STAGE(1, 64);
  int cur = 0;
  for (int i = 0; i < ntiles; i++) {
    const int t0 = i * 64;
    asm volatile("s_waitcnt vmcnt(4)" ::: "memory");
    __builtin_amdgcn_s_barrier();
    __builtin_amdgcn_sched_barrier(0);
    if (t0 < mybound) {
      const u16* kb = &Kl[cur][0];
      const u16* vb = &Vl[cur][0];
      // QK^T (swapped): sc[tt] = S^T tile rows t=t0+tt*16+l4*4+r, col s=l15
      f4v sc[4] = {};
      __builtin_amdgcn_s_setprio(1);
#pragma unroll
      for (int tt = 0; tt < 4; tt++) {
        s8v kf0 = *(const s8v*)(kb + (tt * 16 + l15) * 128 + xk[0]);
        s8v kf1 = *(const s8v*)(kb + (tt * 16 + l15) * 128 + xk[1]);
        s8v kf2 = *(const s8v*)(kb + (tt * 16 + l15) * 128 + xk[2]);
        s8v kf3 = *(const s8v*)(kb + (tt * 16 + l15) * 128 + xk[3]);
        sc[tt] = __builtin_amdgcn_mfma_f32_16x16x32_bf16(kf0, qf[0], sc[tt], 0, 0, 0);
        sc[tt] = __builtin_amdgcn_mfma_f32_16x16x32_bf16(kf1, qf[1], sc[tt], 0, 0, 0);
        sc[tt] = __builtin_amdgcn_mfma_f32_16x16x32_bf16(kf2, qf[2], sc[tt], 0, 0, 0);
        sc[tt] = __builtin_amdgcn_mfma_f32_16x16x32_bf16(kf3, qf[3], sc[tt], 0, 0, 0);
      }
      __builtin_amdgcn_s_setprio(0);
      // causal mask (diagonal tiles only)
      if (t0 + 63 > swp) {
#pragma unroll
        for (int tt = 0; tt < 4; tt++)
#pragma unroll
          for (int r = 0; r < 4; r++) {
            int tg = t0 + tt * 16 + l4 * 4 + r;
            if (tg > swp + l15) sc[tt][r] = -1e30f;
          }
      }
      // in-register online softmax (lane owns column s)
      float mx = sc[0][0];
#pragma unroll
      for (int tt = 0; tt < 4; tt++)
#pragma unroll
        for (int r = 0; r < 4; r++) mx = fmaxf(mx, sc[tt][r]);
      mx = fmaxf(mx, __shfl_xor(mx, 16));
      mx = fmaxf(mx, __shfl_xor(mx, 32));
      if (__any(mx > m2 + 8.f)) {              // T13 defer-max
        float mn = fmaxf(m2, mx);
        float sf = exp2f((m2 - mn) * 1.44269504f);
        m2 = mn; l2 *= sf;
#pragma unroll
        for (int dd = 0; dd < 8; dd++)
#pragma unroll
          for (int r = 0; r < 4; r++) o[dd][r] *= sf;
      }
      u32 pk[4][2];
      float sum = 0.f;
#pragma unroll
      for (int tt = 0; tt < 4; tt++) {
        float p0 = exp2f((sc[tt][0] - m2) * 1.44269504f);
        float p1 = exp2f((sc[tt][1] - m2) * 1.44269504f);
        float p2 = exp2f((sc[tt][2] - m2) * 1.44269504f);
        float p3 = exp2f((sc[tt][3] - m2) * 1.44269504f);
        sum += (p0 + p1) + (p2 + p3);
        pk[tt][0] = cvtpk(p0, p1);
        pk[tt][1] = cvtpk(p2, p3);
      }
      sum += __shfl_xor(sum, 16);
      sum += __shfl_xor(sum, 32);
      l2 += sum;
      // P exchange -> PV B-fragments (one per 32-k half), select after shuffle
      s8v pf[2];
#pragma unroll
      for (int ks = 0; ks < 2; ks++) {
        u32 e00 = (u32)__shfl((int)pk[2 * ks][0], src1);
        u32 e01 = (u32)__shfl((int)pk[2 * ks][1], src1);
        u32 e10 = (u32)__shfl((int)pk[2 * ks + 1][0], src1);
        u32 e11 = (u32)__shfl((int)pk[2 * ks + 1][1], src1);
        u32 f00 = (u32)__shfl((int)pk[2 * ks][0], src2);
        u32 f01 = (u32)__shfl((int)pk[2 * ks][1], src2);
        u32 f10 = (u32)__shfl((int)pk[2 * ks + 1][0], src2);
        u32 f11 = (u32)__shfl((int)pk[2 * ks + 1][1], src2);
        u4v fr;
        fr[0] = selhi ? e10 : e00;
        fr[1] = selhi ? e11 : e01;
        fr[2] = selhi ? f10 : f00;
        fr[3] = selhi ? f11 : f01;
        pf[ks] = __builtin_bit_cast(s8v, fr);
      }
      // PV: O^T += V^T * P
      __builtin_amdgcn_s_setprio(1);
#pragma unroll
      for (int dd = 0; dd < 8; dd++) {
        s8v vf0 = *(const s8v*)(vb + (dd * 16 + l15) * 64 + xv[0]);
        s8v vf1 = *(const s8v*)(vb + (dd * 16 + l15) * 64 + xv[1]);
        o[dd] = __builtin_amdgcn_mfma_f32_16x16x32_bf16(vf0, pf[0], o[dd], 0, 0, 0);
        o[dd] = __builtin_amdgcn_mfma_f32_16x16x32_bf16(vf1, pf[1], o[dd], 0, 0, 0);
      }
      __builtin_amdgcn_s_setprio(0);
    }
    __builtin_amdgcn_sched_barrier(0);
    __builtin_amdgcn_s_barrier();
    if (i + 2 < ntiles) STAGE(cur, t0 + 128);
    cur ^= 1;
  }
#undef STAGE
  // epilogue: lane owns column s = swp + l15; d = dd*16 + l4*4 + r
  float inv = 1.f / l2;
  size_t rowoff = ((size_t)(b * SQ + swp + l15)) * HDIM + h * HD_;
#pragma unroll
  for (int dd = 0; dd < 8; dd++) {
    *(u32*)(ctx + rowoff + dd * 16 + l4 * 4)     = cvtpk(o[dd][0] * inv, o[dd][1] * inv);
    *(u32*)(ctx + rowoff + dd * 16 + l4 * 4 + 2) = cvtpk(o[dd][2] * inv, o[dd][3] * inv);
  }
}

extern "C" void kernel_launch(void* const* d_in, const int* in_sizes, int n_in,
                              void* d_out, int out_size, void* d_ws, size_t ws_size,
                              hipStream_t stream) {
  const float* x     = (const float*)d_in[0];
  const float* wq    = (const float*)d_in[1];
  const float* wk    = (const float*)d_in[2];
  const float* wv    = (const float*)d_in[3];
  const float* wo    = (const float*)d_in[4];
  const float* rms_w = (const float*)d_in[5];
  const int*   pos   = (const int*)d_in[6];

  u16* w = (u16*)d_ws;
  u16* xb   = w;                    // 8388608  x bf16 [4096,2048]; later reused as ctx
  u16* wqt  = xb   + 8388608;       // wqt/wkt/wvt contiguous = QKV B^T [4096][2048]
  u16* wkt  = wqt  + 4194304;
  u16* wvt  = wkt  + 2097152;
  u16* wot  = wvt  + 2097152;
  u16* qkvraw = wot + 4194304;      // 16777216 fused QKV GEMM out [4096][4096]
  u16* kkb  = qkvraw + 16777216;    // kk[b,kv,s,d]
  u16* vtb  = kkb  + 4194304;       // vt[b,kv,d,s]
  u16* qqb  = wqt;                  // alias over wqt..wvt (dead after QKV gemm)
  u16* ctxb = xb;                   // alias over xb (dead after gemms)

  k_cast<<<8192, 256, 0, stream>>>(x, xb, 2097152);
  k_transpose4<<<dim3(64, 64, 4), 256, 0, stream>>>(wq, wk, wv, wo, wqt, wkt, wvt, wot);

  // fused QKV projection: [4096,2048] x [2048,4096] -> [4096,4096]
  k_gemm<0><<<dim3(32, 32), 256, 0, stream>>>(xb, wqt, qkvraw, 4096, 4096, 2048);

  k_normrope<<<4096, 256, 0, stream>>>(qkvraw, rms_w, pos, qqb, kkb, vtb);

  k_attn<<<dim3(16, 16, 2), 512, 0, stream>>>(qqb, kkb, vtb, ctxb);

  k_gemm<1><<<dim3(16, 32), 256, 0, stream>>>(ctxb, wot, d_out, 4096, 2048, 2048);
}

// Round 8
// 250.459 us; speedup vs baseline: 2.8947x; 1.0815x over previous
//
#include <hip/hip_runtime.h>
#include <hip/hip_bf16.h>
#include <stdint.h>

typedef unsigned short u16;
typedef uint32_t u32;
typedef __attribute__((ext_vector_type(8))) short s8v;   // 8 bf16 (4 VGPRs)
typedef __attribute__((ext_vector_type(4))) float f4v;   // 4 fp32
typedef __attribute__((ext_vector_type(4))) unsigned int u4v;

#define SQ   2048
#define HDIM 2048
#define HD_  128
#define NH_  16
#define NKV_ 8

__device__ __forceinline__ u16 f2b(float f) {
  uint32_t u = __builtin_bit_cast(uint32_t, f);
  u += 0x7fffu + ((u >> 16) & 1u);
  return (u16)(u >> 16);
}
__device__ __forceinline__ float b2f(u16 v) {
  uint32_t u = ((uint32_t)v) << 16;
  return __builtin_bit_cast(float, u);
}
__device__ __forceinline__ u32 pk2(float lo, float hi) {
  return (u32)f2b(lo) | ((u32)f2b(hi) << 16);
}
// hardware packed f32x2 -> bf16x2 (RNE), single VALU op
__device__ __forceinline__ u32 cvtpk(float lo, float hi) {
  u32 r;
  asm("v_cvt_pk_bf16_f32 %0, %1, %2" : "=v"(r) : "v"(lo), "v"(hi));
  return r;
}

// ---------------- cast f32 -> bf16, 4 elems/thread ----------------
__global__ __launch_bounds__(256) void k_cast(const float* __restrict__ in,
                                              u16* __restrict__ out, int n4) {
  int i = blockIdx.x * 256 + threadIdx.x;
  if (i >= n4) return;
  f4v v = *(const f4v*)(in + (size_t)i * 4);
  union { u16 s[4]; uint64_t u; } o;
  o.s[0] = f2b(v[0]); o.s[1] = f2b(v[1]); o.s[2] = f2b(v[2]); o.s[3] = f2b(v[3]);
  *(uint64_t*)(out + (size_t)i * 4) = o.u;
}

// ---------------- fused transpose+cast for all 4 weights ----------------
__global__ __launch_bounds__(256) void k_transpose4(const float* __restrict__ wq,
                                                    const float* __restrict__ wk,
                                                    const float* __restrict__ wv,
                                                    const float* __restrict__ wo,
                                                    u16* __restrict__ wqt,
                                                    u16* __restrict__ wkt,
                                                    u16* __restrict__ wvt,
                                                    u16* __restrict__ wot) {
  const int z = blockIdx.z;
  const float* in = (z == 0) ? wq : (z == 1) ? wk : (z == 2) ? wv : wo;
  u16* out = (z == 0) ? wqt : (z == 1) ? wkt : (z == 2) ? wvt : wot;
  const int cols = (z == 1 || z == 2) ? 1024 : 2048;
  int c0 = blockIdx.x * 32, r0 = blockIdx.y * 32;
  if (c0 >= cols) return;
  __shared__ float tile[32][33];
  int tx = threadIdx.x & 31, ty = threadIdx.x >> 5;
#pragma unroll
  for (int i = 0; i < 32; i += 8)
    tile[ty + i][tx] = in[(size_t)(r0 + ty + i) * cols + c0 + tx];
  __syncthreads();
#pragma unroll
  for (int i = 0; i < 32; i += 8)
    out[(size_t)(c0 + ty + i) * 2048 + r0 + tx] = f2b(tile[tx][ty + i]);
}

// ---------------- bf16 GEMM 128²: C[M,N] = A[M,K] * Bt[N,K]^T (wo path) ------
template <int F32OUT>
__global__ __launch_bounds__(256) void k_gemm(const u16* __restrict__ A,
                                              const u16* __restrict__ Bt,
                                              void* __restrict__ C,
                                              int M, int N, int K) {
  __shared__ __align__(16) u16 As[128 * 64];
  __shared__ __align__(16) u16 Bs[128 * 64];
  const int tid = threadIdx.x;
  const int lane = tid & 63, wvi = tid >> 6;
  const int wm = wvi >> 1, wn = wvi & 1;
  const int l15 = lane & 15, l4 = lane >> 4;
  const int m0 = blockIdx.y * 128, n0 = blockIdx.x * 128;
  auto* As3 = (__attribute__((address_space(3))) char*)As;
  auto* Bs3 = (__attribute__((address_space(3))) char*)Bs;
  int srow[4], soff[4];
#pragma unroll
  for (int i = 0; i < 4; i++) {
    int slot = wvi * 4096 + i * 1024 + lane * 16;
    int r = slot >> 7;
    int gc = ((slot >> 4) & 7) ^ (r & 7);
    srow[i] = r; soff[i] = gc * 16;
  }
  f4v acc[4][4] = {};
  for (int k0 = 0; k0 < K; k0 += 64) {
#pragma unroll
    for (int i = 0; i < 4; i++) {
      const char* gA = (const char*)(A + (size_t)(m0 + srow[i]) * K + k0) + soff[i];
      const char* gB = (const char*)(Bt + (size_t)(n0 + srow[i]) * K + k0) + soff[i];
      __builtin_amdgcn_global_load_lds((__attribute__((address_space(1))) void*)gA,
                                       (__attribute__((address_space(3))) void*)(As3 + wvi * 4096 + i * 1024),
                                       16, 0, 0);
      __builtin_amdgcn_global_load_lds((__attribute__((address_space(1))) void*)gB,
                                       (__attribute__((address_space(3))) void*)(Bs3 + wvi * 4096 + i * 1024),
                                       16, 0, 0);
    }
    __syncthreads();
#pragma unroll
    for (int kk = 0; kk < 2; kk++) {
      s8v af[4], bf[4];
#pragma unroll
      for (int i = 0; i < 4; i++) {
        int ra = wm * 64 + i * 16 + l15;
        af[i] = *(const s8v*)((const char*)As + ra * 128 +
                              ((kk * 64 + l4 * 16) ^ ((ra & 7) << 4)));
        int rb = wn * 64 + i * 16 + l15;
        bf[i] = *(const s8v*)((const char*)Bs + rb * 128 +
                              ((kk * 64 + l4 * 16) ^ ((rb & 7) << 4)));
      }
#pragma unroll
      for (int i = 0; i < 4; i++)
#pragma unroll
        for (int j = 0; j < 4; j++)
          acc[i][j] = __builtin_amdgcn_mfma_f32_16x16x32_bf16(af[i], bf[j], acc[i][j], 0, 0, 0);
    }
    __syncthreads();
  }
#pragma unroll
  for (int i = 0; i < 4; i++) {
#pragma unroll
    for (int j = 0; j < 4; j++) {
      int mb = m0 + wm * 64 + i * 16 + l4 * 4;
      int nn = n0 + wn * 64 + j * 16 + l15;
#pragma unroll
      for (int r = 0; r < 4; r++) {
        float v = acc[i][j][r];
        if (F32OUT) ((float*)C)[(size_t)(mb + r) * N + nn] = v;
        else        ((u16*)C)[(size_t)(mb + r) * N + nn]  = f2b(v);
      }
    }
  }
}

// ---------------- bf16 GEMM 256²: counted-vmcnt structure (QKV path) ---------
// BM=BN=256, BK=64, 8 waves (2M x 4N), per-wave 128x64 out (acc 8x4 frags).
// LDS 128KB: 2 dbuf x (A 32KB + B 32KB), rule-21 swizzle (proven 0-conflict).
// Loop: vmcnt(8) at tile top (next tile's 8 loads stay in flight; never 0
// except peeled last tile), raw s_barrier, 4 quadrant phases of 16 MFMA,
// post barrier + stage t+2 into just-freed buffer (attn-v7-proven pattern).
__global__ __launch_bounds__(512, 2) void k_gemm256(const u16* __restrict__ A,
                                                    const u16* __restrict__ Bt,
                                                    u16* __restrict__ C,
                                                    int M, int N, int K) {
  __shared__ __align__(16) u16 Al[2][256 * 64];   // 64 KB
  __shared__ __align__(16) u16 Bl[2][256 * 64];   // 64 KB
  const int tid = threadIdx.x;
  const int lane = tid & 63, wid = tid >> 6;
  const int wm = wid >> 2, wn = wid & 3;
  const int l15 = lane & 15, l4 = lane >> 4;
  const int m0 = blockIdx.y * 256, n0 = blockIdx.x * 256;
  auto* A3 = (__attribute__((address_space(3))) char*)&Al[0][0];
  auto* B3 = (__attribute__((address_space(3))) char*)&Bl[0][0];
  // staging maps: linear LDS dest, inverse-swizzled global source (rule 21)
  int srow[4], soff[4];
#pragma unroll
  for (int j = 0; j < 4; j++) {
    int slot = j * 8192 + tid * 16;                // byte slot in 32KB tile
    srow[j] = slot >> 7;                           // row 0..255 (128B rows)
    soff[j] = (((slot >> 4) & 7) ^ (srow[j] & 7)) * 16;
  }
  // swizzled read chunk offsets (row&7 == l15&7 for all fragment rows)
  int xk2[2];
#pragma unroll
  for (int ks = 0; ks < 2; ks++) xk2[ks] = (((ks * 4 + l4) ^ (l15 & 7)) << 4);

#define STAGE256(buf, k0s)                                                        \
  do {                                                                            \
    _Pragma("unroll")                                                             \
    for (int j = 0; j < 4; j++) {                                                 \
      const char* gA = (const char*)(A + (size_t)(m0 + srow[j]) * K + (k0s)) + soff[j]; \
      __builtin_amdgcn_global_load_lds(                                           \
          (const __attribute__((address_space(1))) void*)gA,                      \
          (__attribute__((address_space(3))) void*)(A3 + (buf) * 32768 + j * 8192 + tid * 16), \
          16, 0, 0);                                                              \
      const char* gB = (const char*)(Bt + (size_t)(n0 + srow[j]) * K + (k0s)) + soff[j]; \
      __builtin_amdgcn_global_load_lds(                                           \
          (const __attribute__((address_space(1))) void*)gB,                      \
          (__attribute__((address_space(3))) void*)(B3 + (buf) * 32768 + j * 8192 + tid * 16), \
          16, 0, 0);                                                              \
    }                                                                             \
  } while (0)

  f4v acc[8][4] = {};
  STAGE256(0, 0);
  STAGE256(1, 64);
  const int nK = K >> 6;
  for (int t = 0; t < nK; t++) {
    if (t == nK - 1) asm volatile("s_waitcnt vmcnt(0)" ::: "memory");
    else             asm volatile("s_waitcnt vmcnt(8)" ::: "memory");
    __builtin_amdgcn_s_barrier();
    __builtin_amdgcn_sched_barrier(0);
    const char* Ab = (const char*)&Al[0][0] + (t & 1) * 32768;
    const char* Bb = (const char*)&Bl[0][0] + (t & 1) * 32768;
#pragma unroll
    for (int qm = 0; qm < 2; qm++)
#pragma unroll
      for (int qn = 0; qn < 2; qn++) {
        s8v af[4][2], bf2[2][2];
#pragma unroll
        for (int i2 = 0; i2 < 4; i2++) {
          int row = wm * 128 + (qm * 4 + i2) * 16 + l15;
#pragma unroll
          for (int ks = 0; ks < 2; ks++)
            af[i2][ks] = *(const s8v*)(Ab + row * 128 + xk2[ks]);
        }
#pragma unroll
        for (int j2 = 0; j2 < 2; j2++) {
          int row = wn * 64 + (qn * 2 + j2) * 16 + l15;
#pragma unroll
          for (int ks = 0; ks < 2; ks++)
            bf2[j2][ks] = *(const s8v*)(Bb + row * 128 + xk2[ks]);
        }
        __builtin_amdgcn_s_setprio(1);
#pragma unroll
        for (int i2 = 0; i2 < 4; i2++)
#pragma unroll
          for (int j2 = 0; j2 < 2; j2++)
#pragma unroll
            for (int ks = 0; ks < 2; ks++)
              acc[qm * 4 + i2][qn * 2 + j2] = __builtin_amdgcn_mfma_f32_16x16x32_bf16(
                  af[i2][ks], bf2[j2][ks], acc[qm * 4 + i2][qn * 2 + j2], 0, 0, 0);
        __builtin_amdgcn_s_setprio(0);
      }
    __builtin_amdgcn_sched_barrier(0);
    if (t + 2 < nK) {
      __builtin_amdgcn_s_barrier();
      STAGE256(t & 1, (t + 2) * 64);
    }
  }
#undef STAGE256
  // epilogue: row = m-frag row + l4*4 + r (A operand), col = l15 (B operand)
#pragma unroll
  for (int mi = 0; mi < 8; mi++)
#pragma unroll
    for (int ni = 0; ni < 4; ni++) {
      int mb = m0 + wm * 128 + mi * 16 + l4 * 4;
      int nn = n0 + wn * 64 + ni * 16 + l15;
#pragma unroll
      for (int r = 0; r < 4; r++)
        C[(size_t)(mb + r) * N + nn] = f2b(acc[mi][ni][r]);
    }
}

// ---------------- RMSNorm + RoPE + layout repack (fused-QKV input) ----------------
__global__ __launch_bounds__(256) void k_normrope(const u16* __restrict__ qkv,
                                                  const float* __restrict__ rms_w,
                                                  const int* __restrict__ pos_arr,
                                                  u16* __restrict__ qq,
                                                  u16* __restrict__ kko,
                                                  u16* __restrict__ vto) {
  int idx = blockIdx.x;            // b*SQ + s
  int b = idx >> 11, s = idx & 2047;
  int t = threadIdx.x;
  __shared__ float part[256];
  __shared__ float rstdq[16], rstdk[8];
  __shared__ float lcos[64], lsin[64];
  float pos = (float)pos_arr[s];
  if (t < 64) {
    float ang = pos * exp2f(-0.20762050593046f * (float)t);
    float sn, cs;
    sincosf(ang, &sn, &cs);
    lcos[t] = cs; lsin[t] = sn;
  }
  const u16* qr = qkv + (size_t)idx * 4096;
  const u16* kr = qr + 2048;
  const u16* vr = qr + 3072;
  // ---- Q ----
  int h = t & 15, ch = t >> 4;
  float qv[8]; float ss = 0.f;
#pragma unroll
  for (int j = 0; j < 8; j++) {
    float v = b2f(qr[(ch * 8 + j) * 16 + h]);
    qv[j] = v; ss += v * v;
  }
  part[t] = ss;
  __syncthreads();
  if (t < 16) {
    float tot = 0.f;
#pragma unroll
    for (int c = 0; c < 16; c++) tot += part[c * 16 + t];
    rstdq[t] = rsqrtf(tot * (1.f / 128.f) + 1e-6f);
  }
  __syncthreads();
  {
    float rs = rstdq[h];
    s8v ov;
#pragma unroll
    for (int p = 0; p < 4; p++) {
      int d0 = ch * 8 + p * 2;
      float v0 = qv[p * 2]     * rs * rms_w[d0];
      float v1 = qv[p * 2 + 1] * rs * rms_w[d0 + 1];
      float cs = lcos[d0 >> 1], sn = lsin[d0 >> 1];
      ov[p * 2]     = (short)f2b((v0 * cs - v1 * sn) * 0.08838834764831845f);
      ov[p * 2 + 1] = (short)f2b((v0 * sn + v1 * cs) * 0.08838834764831845f);
    }
    *(s8v*)(qq + ((size_t)(b * 16 + h) * SQ + s) * HD_ + ch * 8) = ov;
  }
  __syncthreads();
  // ---- K/V (threads < 128) ----
  int kv = t & 7, ch2 = t >> 3;
  float kvs[8]; float ssk = 0.f;
  if (t < 128) {
#pragma unroll
    for (int j = 0; j < 8; j++) {
      float v = b2f(kr[(ch2 * 8 + j) * 8 + kv]);
      kvs[j] = v; ssk += v * v;
    }
    part[t] = ssk;
  }
  __syncthreads();
  if (t < 8) {
    float tot = 0.f;
#pragma unroll
    for (int c = 0; c < 16; c++) tot += part[c * 8 + t];
    rstdk[t] = rsqrtf(tot * (1.f / 128.f) + 1e-6f);
  }
  __syncthreads();
  if (t < 128) {
    float rs = rstdk[kv];
    s8v ov;
#pragma unroll
    for (int p = 0; p < 4; p++) {
      int d0 = ch2 * 8 + p * 2;
      float v0 = kvs[p * 2]     * rs * rms_w[d0];
      float v1 = kvs[p * 2 + 1] * rs * rms_w[d0 + 1];
      float cs = lcos[d0 >> 1], sn = lsin[d0 >> 1];
      ov[p * 2]     = (short)f2b(v0 * cs - v1 * sn);
      ov[p * 2 + 1] = (short)f2b(v0 * sn + v1 * cs);
    }
    *(s8v*)(kko + ((size_t)(b * 8 + kv) * SQ + s) * HD_ + ch2 * 8) = ov;
#pragma unroll
    for (int j = 0; j < 8; j++) {
      int d = ch2 * 8 + j;
      vto[((size_t)(b * 8 + kv) * HD_ + d) * SQ + s] = vr[d * 8 + kv];
    }
  }
}

// ---------------- causal flash attention v7 (unchanged from round 7) ------------
__global__ __launch_bounds__(512, 2) void k_attn(const u16* __restrict__ qq,
                                                 const u16* __restrict__ kk,
                                                 const u16* __restrict__ vt,
                                                 u16* __restrict__ ctx) {
  const int tile = (blockIdx.z == 1) ? (15 - (int)blockIdx.x) : (int)blockIdx.x;
  const int s0 = tile * 128;
  const int h  = blockIdx.y;
  const int b  = blockIdx.z;
  const int kvh = h >> 1;
  const int tid = threadIdx.x, lane = tid & 63, w = tid >> 6;
  const int l15 = lane & 15, l4 = lane >> 4;
  __shared__ __align__(16) u16 Kl[2][64 * 128];   // [buf][t][d]  16KB each
  __shared__ __align__(16) u16 Vl[2][128 * 64];   // [buf][d][t]  16KB each
  auto* K3 = (__attribute__((address_space(3))) char*)&Kl[0][0];
  auto* V3 = (__attribute__((address_space(3))) char*)&Vl[0][0];
  const u16* qbase = qq + (size_t)(b * 16 + h) * SQ * HD_;
  const u16* kbase = kk + (size_t)(b * 8 + kvh) * SQ * HD_;
  const u16* vbase = vt + (size_t)(b * 8 + kvh) * HD_ * SQ;
  const int swp = s0 + w * 16;
  const int mybound = swp + 16;
  const int ntiles = 2 * tile + 2;

  int krow[2], kgo[2], vrow[2], vgo[2];
#pragma unroll
  for (int j = 0; j < 2; j++) {
    int s = j * 8192 + tid * 16;
    krow[j] = s >> 8;
    kgo[j]  = (((s >> 4) & 15) ^ (krow[j] & 7)) * 8;
    vrow[j] = s >> 7;
    vgo[j]  = (((s >> 4) & 7) ^ (vrow[j] & 7)) * 8;
  }

#define STAGE(buf, t0s)                                                           \
  do {                                                                            \
    _Pragma("unroll")                                                             \
    for (int j = 0; j < 2; j++) {                                                 \
      const u16* gk = kbase + (size_t)((t0s) + krow[j]) * HD_ + kgo[j];           \
      __builtin_amdgcn_global_load_lds(                                           \
          (const __attribute__((address_space(1))) void*)gk,                      \
          (__attribute__((address_space(3))) void*)(K3 + (buf) * 16384 + j * 8192 + tid * 16), \
          16, 0, 0);                                                              \
      const u16* gv = vbase + (size_t)vrow[j] * SQ + (t0s) + vgo[j];              \
      __builtin_amdgcn_global_load_lds(                                           \
          (const __attribute__((address_space(1))) void*)gv,                      \
          (__attribute__((address_space(3))) void*)(V3 + (buf) * 16384 + j * 8192 + tid * 16), \
          16, 0, 0);                                                              \
    }                                                                             \
  } while (0)

  s8v qf[4];
#pragma unroll
  for (int c = 0; c < 4; c++)
    qf[c] = *(const s8v*)(qbase + (size_t)(swp + l15) * HD_ + c * 32 + l4 * 8);

  f4v o[8] = {};
  float m2 = -1e30f, l2 = 0.f;

  const int src1 = ((l4 & 1) << 5) + l15;
  const int src2 = src1 + 16;
  const bool selhi = (l4 >> 1) != 0;
  const int swzk = (l15 & 7);

  int xk[4], xv[2];
#pragma unroll
  for (int c = 0; c < 4; c++) xk[c] = ((c * 4 + l4) ^ swzk) * 8;
#pragma unroll
  for (int ks = 0; ks < 2; ks++) xv[ks] = ((ks * 4 + l4) ^ swzk) * 8;

  STAGE(0, 0);
  STAGE(1, 64);
  int cur = 0;
  for (int i = 0; i < ntiles; i++) {
    const int t0 = i * 64;
    asm volatile("s_waitcnt vmcnt(4)" ::: "memory");
    __builtin_amdgcn_s_barrier();
    __builtin_amdgcn_sched_barrier(0);
    if (t0 < mybound) {
      const u16* kb = &Kl[cur][0];
      const u16* vb = &Vl[cur][0];
      f4v sc[4] = {};
      __builtin_amdgcn_s_setprio(1);
#pragma unroll
      for (int tt = 0; tt < 4; tt++) {
        s8v kf0 = *(const s8v*)(kb + (tt * 16 + l15) * 128 + xk[0]);
        s8v kf1 = *(const s8v*)(kb + (tt * 16 + l15) * 128 + xk[1]);
        s8v kf2 = *(const s8v*)(kb + (tt * 16 + l15) * 128 + xk[2]);
        s8v kf3 = *(const s8v*)(kb + (tt * 16 + l15) * 128 + xk[3]);
        sc[tt] = __builtin_amdgcn_mfma_f32_16x16x32_bf16(kf0, qf[0], sc[tt], 0, 0, 0);
        sc[tt] = __builtin_amdgcn_mfma_f32_16x16x32_bf16(kf1, qf[1], sc[tt], 0, 0, 0);
        sc[tt] = __builtin_amdgcn_mfma_f32_16x16x32_bf16(kf2, qf[2], sc[tt], 0, 0, 0);
        sc[tt] = __builtin_amdgcn_mfma_f32_16x16x32_bf16(kf3, qf[3], sc[tt], 0, 0, 0);
      }
      __builtin_amdgcn_s_setprio(0);
      if (t0 + 63 > swp) {
#pragma unroll
        for (int tt = 0; tt < 4; tt++)
#pragma unroll
          for (int r = 0; r < 4; r++) {
            int tg = t0 + tt * 16 + l4 * 4 + r;
            if (tg > swp + l15) sc[tt][r] = -1e30f;
          }
      }
      float mx = sc[0][0];
#pragma unroll
      for (int tt = 0; tt < 4; tt++)
#pragma unroll
        for (int r = 0; r < 4; r++) mx = fmaxf(mx, sc[tt][r]);
      mx = fmaxf(mx, __shfl_xor(mx, 16));
      mx = fmaxf(mx, __shfl_xor(mx, 32));
      if (__any(mx > m2 + 8.f)) {
        float mn = fmaxf(m2, mx);
        float sf = exp2f((m2 - mn) * 1.44269504f);
        m2 = mn; l2 *= sf;
#pragma unroll
        for (int dd = 0; dd < 8; dd++)
#pragma unroll
          for (int r = 0; r < 4; r++) o[dd][r] *= sf;
      }
      u32 pk[4][2];
      float sum = 0.f;
#pragma unroll
      for (int tt = 0; tt < 4; tt++) {
        float p0 = exp2f((sc[tt][0] - m2) * 1.44269504f);
        float p1 = exp2f((sc[tt][1] - m2) * 1.44269504f);
        float p2 = exp2f((sc[tt][2] - m2) * 1.44269504f);
        float p3 = exp2f((sc[tt][3] - m2) * 1.44269504f);
        sum += (p0 + p1) + (p2 + p3);
        pk[tt][0] = cvtpk(p0, p1);
        pk[tt][1] = cvtpk(p2, p3);
      }
      sum += __shfl_xor(sum, 16);
      sum += __shfl_xor(sum, 32);
      l2 += sum;
      s8v pf[2];
#pragma unroll
      for (int ks = 0; ks < 2; ks++) {
        u32 e00 = (u32)__shfl((int)pk[2 * ks][0], src1);
        u32 e01 = (u32)__shfl((int)pk[2 * ks][1], src1);
        u32 e10 = (u32)__shfl((int)pk[2 * ks + 1][0], src1);
        u32 e11 = (u32)__shfl((int)pk[2 * ks + 1][1], src1);
        u32 f00 = (u32)__shfl((int)pk[2 * ks][0], src2);
        u32 f01 = (u32)__shfl((int)pk[2 * ks][1], src2);
        u32 f10 = (u32)__shfl((int)pk[2 * ks + 1][0], src2);
        u32 f11 = (u32)__shfl((int)pk[2 * ks + 1][1], src2);
        u4v fr;
        fr[0] = selhi ? e10 : e00;
        fr[1] = selhi ? e11 : e01;
        fr[2] = selhi ? f10 : f00;
        fr[3] = selhi ? f11 : f01;
        pf[ks] = __builtin_bit_cast(s8v, fr);
      }
      __builtin_amdgcn_s_setprio(1);
#pragma unroll
      for (int dd = 0; dd < 8; dd++) {
        s8v vf0 = *(const s8v*)(vb + (dd * 16 + l15) * 64 + xv[0]);
        s8v vf1 = *(const s8v*)(vb + (dd * 16 + l15) * 64 + xv[1]);
        o[dd] = __builtin_amdgcn_mfma_f32_16x16x32_bf16(vf0, pf[0], o[dd], 0, 0, 0);
        o[dd] = __builtin_amdgcn_mfma_f32_16x16x32_bf16(vf1, pf[1], o[dd], 0, 0, 0);
      }
      __builtin_amdgcn_s_setprio(0);
    }
    __builtin_amdgcn_sched_barrier(0);
    __builtin_amdgcn_s_barrier();
    if (i + 2 < ntiles) STAGE(cur, t0 + 128);
    cur ^= 1;
  }
#undef STAGE
  float inv = 1.f / l2;
  size_t rowoff = ((size_t)(b * SQ + swp + l15)) * HDIM + h * HD_;
#pragma unroll
  for (int dd = 0; dd < 8; dd++) {
    *(u32*)(ctx + rowoff + dd * 16 + l4 * 4)     = cvtpk(o[dd][0] * inv, o[dd][1] * inv);
    *(u32*)(ctx + rowoff + dd * 16 + l4 * 4 + 2) = cvtpk(o[dd][2] * inv, o[dd][3] * inv);
  }
}

extern "C" void kernel_launch(void* const* d_in, const int* in_sizes, int n_in,
                              void* d_out, int out_size, void* d_ws, size_t ws_size,
                              hipStream_t stream) {
  const float* x     = (const float*)d_in[0];
  const float* wq    = (const float*)d_in[1];
  const float* wk    = (const float*)d_in[2];
  const float* wv    = (const float*)d_in[3];
  const float* wo    = (const float*)d_in[4];
  const float* rms_w = (const float*)d_in[5];
  const int*   pos   = (const int*)d_in[6];

  u16* w = (u16*)d_ws;
  u16* xb   = w;                    // 8388608  x bf16 [4096,2048]; later reused as ctx
  u16* wqt  = xb   + 8388608;       // wqt/wkt/wvt contiguous = QKV B^T [4096][2048]
  u16* wkt  = wqt  + 4194304;
  u16* wvt  = wkt  + 2097152;
  u16* wot  = wvt  + 2097152;
  u16* qkvraw = wot + 4194304;      // 16777216 fused QKV GEMM out [4096][4096]
  u16* kkb  = qkvraw + 16777216;    // kk[b,kv,s,d]
  u16* vtb  = kkb  + 4194304;       // vt[b,kv,d,s]
  u16* qqb  = wqt;                  // alias over wqt..wvt (dead after QKV gemm)
  u16* ctxb = xb;                   // alias over xb (dead after gemms)

  k_cast<<<8192, 256, 0, stream>>>(x, xb, 2097152);
  k_transpose4<<<dim3(64, 64, 4), 256, 0, stream>>>(wq, wk, wv, wo, wqt, wkt, wvt, wot);

  // fused QKV projection: [4096,2048] x [2048,4096] -> [4096,4096], 256² tiles
  k_gemm256<<<dim3(16, 16), 512, 0, stream>>>(xb, wqt, qkvraw, 4096, 4096, 2048);

  k_normrope<<<4096, 256, 0, stream>>>(qkvraw, rms_w, pos, qqb, kkb, vtb);

  k_attn<<<dim3(16, 16, 2), 512, 0, stream>>>(qqb, kkb, vtb, ctxb);

  k_gemm<1><<<dim3(16, 32), 256, 0, stream>>>(ctxb, wot, d_out, 4096, 2048, 2048);
}